// Round 3
// baseline (315.078 us; speedup 1.0000x reference)
//
#include <hip/hip_runtime.h>
#include <hip/hip_bf16.h>

typedef unsigned short u16;
typedef unsigned int u32;
typedef __attribute__((ext_vector_type(8))) short bf16x8;
typedef __attribute__((ext_vector_type(4))) float f32x4;

#define NEXP 8
#define NTOK 4096
#define DDIM 1024
#define MAX_TILES 80

__device__ __forceinline__ u16 f2bf(float f) {
    u32 u = __float_as_uint(f);
    u += 0x7fff + ((u >> 16) & 1);  // RNE
    return (u16)(u >> 16);
}

__device__ __forceinline__ void gload16(const void* g, void* l) {
    __builtin_amdgcn_global_load_lds((const __attribute__((address_space(1))) u32*)g,
                                     (__attribute__((address_space(3))) u32*)l, 16, 0, 0);
}

// ---------------- fused fp32 -> bf16 convert for x,w1,w3,w2 (contig output) -------------
__global__ __launch_bounds__(256) void cvt_all_kernel(const float* __restrict__ x,
                                                      const float* __restrict__ w1,
                                                      const float* __restrict__ w3,
                                                      const float* __restrict__ w2,
                                                      u16* __restrict__ out) {
    const int N8 = 3670016;  // 28M / 8
    int stride = gridDim.x * blockDim.x;
    for (int i = blockIdx.x * blockDim.x + threadIdx.x; i < N8; i += stride) {
        const float* src;
        if (i < 524288)        src = x  + (size_t)i * 8;
        else if (i < 1572864)  src = w1 + ((size_t)i - 524288) * 8;
        else if (i < 2621440)  src = w3 + ((size_t)i - 1572864) * 8;
        else                   src = w2 + ((size_t)i - 2621440) * 8;
        float4 a = ((const float4*)src)[0], b = ((const float4*)src)[1];
        uint4 o;
        o.x = (u32)f2bf(a.x) | ((u32)f2bf(a.y) << 16);
        o.y = (u32)f2bf(a.z) | ((u32)f2bf(a.w) << 16);
        o.z = (u32)f2bf(b.x) | ((u32)f2bf(b.y) << 16);
        o.w = (u32)f2bf(b.z) | ((u32)f2bf(b.w) << 16);
        *(uint4*)(out + (size_t)i * 8) = o;
    }
}

// ---------------- gating: wave-per-token, 1024 blocks -----------------------------------
// ctl layout (ints): [0..8) counts, [8..16) cursors, [16..25) offsets, [25] ntiles,
//                    [32..112) tile_expert, [112..192) tile_rowbase, [192..272) tile_segend
__global__ __launch_bounds__(256) void gate_kernel(const float* __restrict__ x,
                                                   const float* __restrict__ gw,
                                                   int* __restrict__ t2i, float* __restrict__ t2w,
                                                   int* __restrict__ ctl) {
    __shared__ float sgw[NEXP * DDIM];  // 32 KB, chunk-swizzled: phys q = q ^ ((l+(l>>2))&3)
    int tid = threadIdx.x;
    for (int c = tid; c < 2048; c += 256) {
        float4 v = ((const float4*)gw)[c];
        int l = (c >> 2) & 63, q = c & 3;
        int ls = (l + (l >> 2)) & 3;
        ((float4*)sgw)[(c & ~3) | (q ^ ls)] = v;
    }
    __syncthreads();
    int wv = tid >> 6, lane = tid & 63;
    int t = blockIdx.x * 4 + wv;
    const float4* xr = (const float4*)(x + (size_t)t * DDIM);
    float4 xv[4];
#pragma unroll
    for (int q = 0; q < 4; q++) xv[q] = xr[lane * 4 + q];
    int ls = (lane + (lane >> 2)) & 3;
    float acc[NEXP];
#pragma unroll
    for (int e = 0; e < NEXP; e++) acc[e] = 0.f;
#pragma unroll
    for (int e = 0; e < NEXP; e++) {
#pragma unroll
        for (int q = 0; q < 4; q++) {
            float4 g = ((const float4*)sgw)[e * 256 + lane * 4 + (q ^ ls)];
            acc[e] += xv[q].x * g.x + xv[q].y * g.y + xv[q].z * g.z + xv[q].w * g.w;
        }
    }
#pragma unroll
    for (int e = 0; e < NEXP; e++) {
        float v = acc[e];
#pragma unroll
        for (int off = 32; off; off >>= 1) v += __shfl_xor(v, off, 64);
        acc[e] = v;
    }
    if (lane == 0) {
        float m = acc[0];
#pragma unroll
        for (int e = 1; e < NEXP; e++) m = fmaxf(m, acc[e]);
        float p[NEXP]; float s = 0.f;
#pragma unroll
        for (int e = 0; e < NEXP; e++) { p[e] = __expf(acc[e] - m); s += p[e]; }
        float inv = 1.f / s;
        float best = -1.f, sec = -1.f; int bi = 0, si = 0;
#pragma unroll
        for (int e = 0; e < NEXP; e++) {
            float pe = p[e] * inv;
            if (pe > best) { sec = best; si = bi; best = pe; bi = e; }
            else if (pe > sec) { sec = pe; si = e; }
        }
        t2i[2 * t] = bi;  t2i[2 * t + 1] = si;
        t2w[2 * t] = best; t2w[2 * t + 1] = sec;
        atomicAdd(&ctl[bi], 1);
        atomicAdd(&ctl[si], 1);
    }
}

// ---------------- schedule: prefix offsets + row-tile list (single thread) --------------
__global__ void schedule_kernel(int* ctl) {
    int* counts = ctl;
    int* cursors = ctl + 8;
    int* offs = ctl + 16;
    int* te = ctl + 32;
    int* tr = ctl + 112;
    int* ts = ctl + 192;
    int o = 0, tt = 0;
    for (int e = 0; e < NEXP; e++) {
        offs[e] = o;
        int n = counts[e];
        for (int r = 0; r < n; r += 128) { te[tt] = e; tr[tt] = o + r; ts[tt] = o + n; tt++; }
        cursors[e] = 0;
        o += n;
    }
    offs[8] = o;
    ctl[25] = tt;
}

// ---------------- scatter: assign slots ------------------------------------------------
__global__ __launch_bounds__(256) void scatter_kernel(const int* __restrict__ t2i,
                                                      const float* __restrict__ t2w,
                                                      int* ctl, int* __restrict__ slot_token,
                                                      float* __restrict__ slot_wt) {
    int t = blockIdx.x * 256 + threadIdx.x;
    int* cursors = ctl + 8;
    const int* offs = ctl + 16;
#pragma unroll
    for (int k = 0; k < 2; k++) {
        int e = t2i[2 * t + k];
        int pos = atomicAdd(&cursors[e], 1);
        int slot = offs[e] + pos;
        slot_token[slot] = t;
        slot_wt[slot] = t2w[2 * t + k];
    }
}

// ---------------- expert GEMMs (BK=32, m97 geometry: 32KB LDS, 4 blocks/CU) ------------
// MODE 0: H=Xg@w1^T, G=Xg@w3^T (dual acc), A = silu(H)*G -> Abuf bf16.  BN=64.
// MODE 1: Y = Abuf@w2^T, epilogue unsafeAtomicAdd(w * Y) into y fp32.   BN=128.
// Rows are 64B (32 bf16) = 4 chunks of 16B. T2 swizzle (rule 21, both-sides):
//   LDS(r,c) holds global (r, c ^ ((r>>1)&3)); dest linear (gload_lds);
//   source chunk for lane l = (l&3) ^ ((l>>3)&3); read chunk = hi ^ ((r>>1)&3).
//   Verified 2-way max (free per m136).
template <int MODE>
__global__ __launch_bounds__(256, 4) void moe_gemm_kernel(
    const u16* __restrict__ Amat, const u16* __restrict__ B1g, const u16* __restrict__ B2g,
    u16* __restrict__ OutB, float* __restrict__ OutY,
    const int* __restrict__ ctl, const int* __restrict__ slot_token,
    const float* __restrict__ slot_wt) {
    constexpr int BN = (MODE == 0) ? 64 : 128;
    constexpr int NB = BN / 32;   // B frags per wave (wave covers BN/2 cols)
    constexpr int NK = 32;        // 1024 / 32

    int tt = blockIdx.x;
    if (tt >= ctl[25]) return;
    int e = ctl[32 + tt];
    int rowbase = ctl[112 + tt];
    int segend = ctl[192 + tt];
    int cb = blockIdx.y;

    __shared__ __align__(16) u16 smem[2 * 128 * 32 + 2 * BN * 32 + ((MODE == 0) ? 2 * 64 * 32 : 0)];
    u16* sA = smem;                  // [2][128][32]
    u16* sB1 = smem + 2 * 128 * 32;  // [2][BN][32]
    u16* sB2 = sB1 + 2 * BN * 32;    // [2][64][32] (MODE 0 only)

    int tid = threadIdx.x;
    int lane = tid & 63;
    int wv = tid >> 6;
    int wrow = wv >> 1, wcol = wv & 1;
    int lr = lane >> 2;                                   // row within 16-row staging group
    int cS = (((lane & 3) ^ ((lane >> 3) & 3)) << 3);     // pre-swizzled source chunk (elems)
    int l15 = lane & 15, hi = lane >> 4;
    int csr = ((hi ^ ((l15 >> 1) & 3)) << 3);             // swizzled read chunk (elems; row base %16==0)

    // Gathered A source rows (2 staging loads per wave, 16 rows each)
    u32 rowA[2];
#pragma unroll
    for (int i = 0; i < 2; i++) {
        int slot = rowbase + wv * 32 + i * 16 + lr;
        if (slot >= segend) slot = rowbase;
        int src = (MODE == 0) ? slot_token[slot] : slot;
        rowA[i] = (u32)src * 1024;
    }
    u32 rowB[2];
    if constexpr (MODE == 0) {
        int r = cb * 64 + wv * 16 + lr;
        rowB[0] = (u32)e * 1048576 + (u32)r * 1024;
        rowB[1] = 0;
    } else {
#pragma unroll
        for (int i = 0; i < 2; i++) {
            int r = cb * 128 + wv * 32 + i * 16 + lr;
            rowB[i] = (u32)e * 1048576 + (u32)r * 1024;
        }
    }

    f32x4 accH[4][NB], accG[(MODE == 0) ? 4 : 1][(MODE == 0) ? NB : 1];
    f32x4 zero = {0.f, 0.f, 0.f, 0.f};
#pragma unroll
    for (int m2 = 0; m2 < 4; m2++)
#pragma unroll
        for (int n = 0; n < NB; n++) accH[m2][n] = zero;
    if constexpr (MODE == 0) {
#pragma unroll
        for (int m2 = 0; m2 < 4; m2++)
#pragma unroll
            for (int n = 0; n < NB; n++) accG[m2][n] = zero;
    }

    auto stage = [&](int buf, int kt) {
        int k0 = kt * 32 + cS;
        gload16(Amat + rowA[0] + k0, sA + buf * 4096 + (wv * 32) * 32);
        gload16(Amat + rowA[1] + k0, sA + buf * 4096 + (wv * 32 + 16) * 32);
        if constexpr (MODE == 0) {
            gload16(B1g + rowB[0] + k0, sB1 + buf * 2048 + (wv * 16) * 32);
            gload16(B2g + rowB[0] + k0, sB2 + buf * 2048 + (wv * 16) * 32);
        } else {
            gload16(B1g + rowB[0] + k0, sB1 + buf * 4096 + (wv * 32) * 32);
            gload16(B1g + rowB[1] + k0, sB1 + buf * 4096 + (wv * 32 + 16) * 32);
        }
    };

    auto compute = [&](int buf) {
        bf16x8 av[4];
#pragma unroll
        for (int m2 = 0; m2 < 4; m2++) {
            int r = wrow * 64 + m2 * 16 + l15;
            av[m2] = *(const bf16x8*)(sA + buf * 4096 + r * 32 + csr);
        }
        bf16x8 b1v[NB];
#pragma unroll
        for (int n = 0; n < NB; n++) {
            int r = wcol * (BN / 2) + n * 16 + l15;
            b1v[n] = *(const bf16x8*)(sB1 + buf * (BN * 32) + r * 32 + csr);
        }
        if constexpr (MODE == 0) {
            bf16x8 b2v[NB];
#pragma unroll
            for (int n = 0; n < NB; n++) {
                int r = wcol * (BN / 2) + n * 16 + l15;
                b2v[n] = *(const bf16x8*)(sB2 + buf * (BN * 32) + r * 32 + csr);
            }
#pragma unroll
            for (int m2 = 0; m2 < 4; m2++)
#pragma unroll
                for (int n = 0; n < NB; n++) {
                    accH[m2][n] = __builtin_amdgcn_mfma_f32_16x16x32_bf16(av[m2], b1v[n], accH[m2][n], 0, 0, 0);
                    accG[m2][n] = __builtin_amdgcn_mfma_f32_16x16x32_bf16(av[m2], b2v[n], accG[m2][n], 0, 0, 0);
                }
        } else {
#pragma unroll
            for (int m2 = 0; m2 < 4; m2++)
#pragma unroll
                for (int n = 0; n < NB; n++)
                    accH[m2][n] = __builtin_amdgcn_mfma_f32_16x16x32_bf16(av[m2], b1v[n], accH[m2][n], 0, 0, 0);
        }
    };

    stage(0, 0);
    for (int kt = 0; kt < NK; ++kt) {
        __syncthreads();
        if (kt + 1 < NK) stage((kt + 1) & 1, kt + 1);
        compute(kt & 1);
    }

    // Epilogue. C/D layout: col = lane&15, row = (lane>>4)*4 + j  [learn_hip m89]
    int colblock = cb * BN + wcol * (BN / 2);
#pragma unroll
    for (int m2 = 0; m2 < 4; m2++) {
        int slotbase = rowbase + wrow * 64 + m2 * 16 + hi * 4;
#pragma unroll
        for (int n = 0; n < NB; n++) {
            int col = colblock + n * 16 + l15;
#pragma unroll
            for (int j = 0; j < 4; j++) {
                int slot = slotbase + j;
                if (slot < segend) {
                    if constexpr (MODE == 0) {
                        float h = accH[m2][n][j], g = accG[m2][n][j];
                        float a = (h / (1.f + __expf(-h))) * g;  // silu(h)*g
                        OutB[(size_t)slot * 1024 + col] = f2bf(a);
                    } else {
                        int tok = slot_token[slot];
                        float wgt = slot_wt[slot];
                        unsafeAtomicAdd(&OutY[(size_t)tok * 1024 + col], accH[m2][n][j] * wgt);
                    }
                }
            }
        }
    }
}

// ---------------- launch ----------------------------------------------------------------
extern "C" void kernel_launch(void* const* d_in, const int* in_sizes, int n_in,
                              void* d_out, int out_size, void* d_ws, size_t ws_size,
                              hipStream_t stream) {
    const float* x  = (const float*)d_in[0];
    const float* gw = (const float*)d_in[1];
    const float* w1 = (const float*)d_in[2];
    const float* w3 = (const float*)d_in[3];
    const float* w2 = (const float*)d_in[4];
    float* y = (float*)d_out;
    char* ws = (char*)d_ws;

    int*   ctl        = (int*)ws;                    // 4 KB control block
    int*   t2i        = (int*)(ws + 4096);           // 32 KB
    float* t2w        = (float*)(ws + 4096 + 32768);
    int*   slot_token = (int*)(ws + 4096 + 65536);
    float* slot_wt    = (float*)(ws + 4096 + 98304);
    u16*   xb   = (u16*)(ws + 262144);               // 4M elems
    u16*   w1b  = xb  + (size_t)4194304;             // 8M elems each
    u16*   w3b  = w1b + (size_t)8388608;
    u16*   w2b  = w3b + (size_t)8388608;
    u16*   Abuf = w2b + (size_t)8388608;             // 8192 x 1024 bf16

    hipMemsetAsync(ctl, 0, 4096, stream);
    hipMemsetAsync(y, 0, (size_t)out_size * sizeof(float), stream);

    cvt_all_kernel<<<2048, 256, 0, stream>>>(x, w1, w3, w2, xb);

    gate_kernel<<<1024, 256, 0, stream>>>(x, gw, t2i, t2w, ctl);
    schedule_kernel<<<1, 1, 0, stream>>>(ctl);
    scatter_kernel<<<16, 256, 0, stream>>>(t2i, t2w, ctl, slot_token, slot_wt);

    moe_gemm_kernel<0><<<dim3(MAX_TILES, 16), 256, 0, stream>>>(
        xb, w1b, w3b, Abuf, nullptr, ctl, slot_token, slot_wt);
    moe_gemm_kernel<1><<<dim3(MAX_TILES, 8), 256, 0, stream>>>(
        Abuf, w2b, nullptr, nullptr, y, ctl, slot_token, slot_wt);
}

// Round 4
// 183.105 us; speedup vs baseline: 1.7208x; 1.7208x over previous
//
#include <hip/hip_runtime.h>
#include <hip/hip_bf16.h>

typedef unsigned short u16;
typedef unsigned int u32;
typedef __attribute__((ext_vector_type(8))) short bf16x8;
typedef __attribute__((ext_vector_type(4))) float f32x4;

#define NEXP 8
#define NTOK 4096
#define DDIM 1024
#define MAX_TILES 80

__device__ __forceinline__ u16 f2bf(float f) {
    u32 u = __float_as_uint(f);
    u += 0x7fff + ((u >> 16) & 1);  // RNE
    return (u16)(u >> 16);
}

__device__ __forceinline__ void gload16(const void* g, void* l) {
    __builtin_amdgcn_global_load_lds((const __attribute__((address_space(1))) u32*)g,
                                     (__attribute__((address_space(3))) u32*)l, 16, 0, 0);
}

// ---------------- fp32 -> bf16 convert for w1,w3,w2 (contig output) ---------------------
__global__ __launch_bounds__(256) void cvt_w_kernel(const float* __restrict__ w1,
                                                    const float* __restrict__ w3,
                                                    const float* __restrict__ w2,
                                                    u16* __restrict__ out) {
    const int N8 = 3145728;  // 24M / 8
    int stride = gridDim.x * blockDim.x;
    for (int i = blockIdx.x * blockDim.x + threadIdx.x; i < N8; i += stride) {
        const float* src;
        if (i < 1048576)       src = w1 + (size_t)i * 8;
        else if (i < 2097152)  src = w3 + ((size_t)i - 1048576) * 8;
        else                   src = w2 + ((size_t)i - 2097152) * 8;
        float4 a = ((const float4*)src)[0], b = ((const float4*)src)[1];
        uint4 o;
        o.x = (u32)f2bf(a.x) | ((u32)f2bf(a.y) << 16);
        o.y = (u32)f2bf(a.z) | ((u32)f2bf(a.w) << 16);
        o.z = (u32)f2bf(b.x) | ((u32)f2bf(b.y) << 16);
        o.w = (u32)f2bf(b.z) | ((u32)f2bf(b.w) << 16);
        *(uint4*)(out + (size_t)i * 8) = o;
    }
}

// ---------------- gating: wave-per-token; NO atomics; also emits xb (bf16 x) ------------
__global__ __launch_bounds__(256) void gate_kernel(const float* __restrict__ x,
                                                   const float* __restrict__ gw,
                                                   int* __restrict__ t2i, float* __restrict__ t2w,
                                                   u16* __restrict__ xb) {
    int tid = threadIdx.x;
    int wv = tid >> 6, lane = tid & 63;
    int t = blockIdx.x * 4 + wv;
    const float4* xr = (const float4*)(x + (size_t)t * DDIM);
    float4 xv[4];
#pragma unroll
    for (int q = 0; q < 4; q++) xv[q] = xr[lane * 4 + q];

    // bf16 copy of x: lane covers elems [lane*16, lane*16+16)
    uint4 o0, o1;
    o0.x = (u32)f2bf(xv[0].x) | ((u32)f2bf(xv[0].y) << 16);
    o0.y = (u32)f2bf(xv[0].z) | ((u32)f2bf(xv[0].w) << 16);
    o0.z = (u32)f2bf(xv[1].x) | ((u32)f2bf(xv[1].y) << 16);
    o0.w = (u32)f2bf(xv[1].z) | ((u32)f2bf(xv[1].w) << 16);
    o1.x = (u32)f2bf(xv[2].x) | ((u32)f2bf(xv[2].y) << 16);
    o1.y = (u32)f2bf(xv[2].z) | ((u32)f2bf(xv[2].w) << 16);
    o1.z = (u32)f2bf(xv[3].x) | ((u32)f2bf(xv[3].y) << 16);
    o1.w = (u32)f2bf(xv[3].z) | ((u32)f2bf(xv[3].w) << 16);
    uint4* xbo = (uint4*)(xb + (size_t)t * DDIM + lane * 16);
    xbo[0] = o0;
    xbo[1] = o1;

    // scores: gw is 32 KB == L1 size, read direct (L1-hot after first block per CU)
    float acc[NEXP];
#pragma unroll
    for (int e = 0; e < NEXP; e++) acc[e] = 0.f;
#pragma unroll
    for (int e = 0; e < NEXP; e++) {
#pragma unroll
        for (int q = 0; q < 4; q++) {
            float4 g = ((const float4*)gw)[e * 256 + lane * 4 + q];
            acc[e] += xv[q].x * g.x + xv[q].y * g.y + xv[q].z * g.z + xv[q].w * g.w;
        }
    }
#pragma unroll
    for (int e = 0; e < NEXP; e++) {
        float v = acc[e];
#pragma unroll
        for (int off = 32; off; off >>= 1) v += __shfl_xor(v, off, 64);
        acc[e] = v;
    }
    if (lane == 0) {
        float m = acc[0];
#pragma unroll
        for (int e = 1; e < NEXP; e++) m = fmaxf(m, acc[e]);
        float p[NEXP]; float s = 0.f;
#pragma unroll
        for (int e = 0; e < NEXP; e++) { p[e] = __expf(acc[e] - m); s += p[e]; }
        float inv = 1.f / s;
        float best = -1.f, sec = -1.f; int bi = 0, si = 0;
#pragma unroll
        for (int e = 0; e < NEXP; e++) {
            float pe = p[e] * inv;
            if (pe > best) { sec = best; si = bi; best = pe; bi = e; }
            else if (pe > sec) { sec = pe; si = e; }
        }
        t2i[2 * t] = bi;  t2i[2 * t + 1] = si;
        t2w[2 * t] = best; t2w[2 * t + 1] = sec;
    }
}

// ---------------- sort: histogram + block scan + stable counting sort (1 block) --------
// ctl layout (ints): [16..25) offsets, [24] total, [25] ntiles,
//                    [32..112) tile_expert, [112..192) tile_rowbase, [192..272) tile_segend
__global__ __launch_bounds__(1024) void sort_kernel(const int* __restrict__ t2i,
                                                    const float* __restrict__ t2w,
                                                    int* __restrict__ ctl,
                                                    int* __restrict__ slot_token,
                                                    float* __restrict__ slot_wt) {
    __shared__ int sb[NEXP][1024];  // 32 KB: per-thread exclusive base per expert
    __shared__ int wsum[16];
    __shared__ int sex[16];
    __shared__ int stot[NEXP];
    __shared__ int soffs[NEXP + 1];
    int tid = threadIdx.x;
    int lane = tid & 63, wv = tid >> 6;

    int4 a = *(const int4*)(t2i + tid * 8);
    int4 b = *(const int4*)(t2i + tid * 8 + 4);
    int ev0 = a.x, ev1 = a.y, ev2 = a.z, ev3 = a.w;
    int ev4 = b.x, ev5 = b.y, ev6 = b.z, ev7 = b.w;
    // 4-bit packed histogram (counts <= 8 per thread)
    u32 cnt = (1u << (ev0 * 4)) + (1u << (ev1 * 4)) + (1u << (ev2 * 4)) + (1u << (ev3 * 4)) +
              (1u << (ev4 * 4)) + (1u << (ev5 * 4)) + (1u << (ev6 * 4)) + (1u << (ev7 * 4));

    for (int e = 0; e < NEXP; e++) {
        int v = (cnt >> (e * 4)) & 15;
        int inc = v;
#pragma unroll
        for (int off = 1; off < 64; off <<= 1) {
            int n = __shfl_up(inc, off, 64);
            if (lane >= off) inc += n;
        }
        if (lane == 63) wsum[wv] = inc;
        __syncthreads();
        if (wv == 0) {
            int w = (lane < 16) ? wsum[lane] : 0;
            int winc = w;
#pragma unroll
            for (int off = 1; off < 16; off <<= 1) {
                int n = __shfl_up(winc, off, 64);
                if (lane >= off) winc += n;
            }
            if (lane < 16) sex[lane] = winc - w;
            if (lane == 15) stot[e] = winc;
        }
        __syncthreads();
        sb[e][tid] = sex[wv] + inc - v;
        __syncthreads();
    }
    if (tid == 0) {
        int o = 0, tt = 0;
        for (int e = 0; e < NEXP; e++) {
            soffs[e] = o;
            ctl[16 + e] = o;
            int n = stot[e];
            for (int r = 0; r < n; r += 128) {
                ctl[32 + tt] = e; ctl[112 + tt] = o + r; ctl[192 + tt] = o + n; tt++;
            }
            o += n;
        }
        soffs[NEXP] = o; ctl[24] = o; ctl[25] = tt;
    }
    __syncthreads();
#pragma unroll
    for (int j = 0; j < 8; j++) {
        int e;
        switch (j) {  // static unroll, ev in regs
            case 0: e = ev0; break; case 1: e = ev1; break; case 2: e = ev2; break;
            case 3: e = ev3; break; case 4: e = ev4; break; case 5: e = ev5; break;
            case 6: e = ev6; break; default: e = ev7; break;
        }
        int base = sb[e][tid];
        sb[e][tid] = base + 1;
        int slot = soffs[e] + base;
        int p = tid * 8 + j;
        slot_token[slot] = p >> 1;
        slot_wt[slot] = t2w[p];
    }
}

// ---------------- expert GEMMs (BK=32, 32KB LDS, 4 blocks/CU) ---------------------------
// MODE 0: H=Xg@w1^T, G=Xg@w3^T (dual acc), A = silu(H)*G -> Abuf bf16.  BN=64.
// MODE 1: Y = Abuf@w2^T, epilogue unsafeAtomicAdd(w * Y) into y fp32.   BN=128.
// Rows are 64B (32 bf16) = 4 chunks of 16B. T2 swizzle (rule 21, both-sides):
//   LDS(r,c) holds global (r, c ^ ((r>>1)&3)); dest linear (gload_lds);
//   source chunk for lane l = (l&3) ^ ((l>>3)&3); read chunk = hi ^ ((r>>1)&3).
template <int MODE>
__global__ __launch_bounds__(256, 4) void moe_gemm_kernel(
    const u16* __restrict__ Amat, const u16* __restrict__ B1g, const u16* __restrict__ B2g,
    u16* __restrict__ OutB, float* __restrict__ OutY,
    const int* __restrict__ ctl, const int* __restrict__ slot_token,
    const float* __restrict__ slot_wt) {
    constexpr int BN = (MODE == 0) ? 64 : 128;
    constexpr int NB = BN / 32;
    constexpr int NK = 32;

    int tt = blockIdx.x;
    if (tt >= ctl[25]) return;
    int e = ctl[32 + tt];
    int rowbase = ctl[112 + tt];
    int segend = ctl[192 + tt];
    int cb = blockIdx.y;

    __shared__ __align__(16) u16 smem[2 * 128 * 32 + 2 * BN * 32 + ((MODE == 0) ? 2 * 64 * 32 : 0)];
    u16* sA = smem;                  // [2][128][32]
    u16* sB1 = smem + 2 * 128 * 32;  // [2][BN][32]
    u16* sB2 = sB1 + 2 * BN * 32;    // [2][64][32] (MODE 0 only)

    int tid = threadIdx.x;
    int lane = tid & 63;
    int wv = tid >> 6;
    int wrow = wv >> 1, wcol = wv & 1;
    int lr = lane >> 2;
    int cS = (((lane & 3) ^ ((lane >> 3) & 3)) << 3);
    int l15 = lane & 15, hi = lane >> 4;
    int csr = ((hi ^ ((l15 >> 1) & 3)) << 3);

    u32 rowA[2];
#pragma unroll
    for (int i = 0; i < 2; i++) {
        int slot = rowbase + wv * 32 + i * 16 + lr;
        if (slot >= segend) slot = rowbase;
        int src = (MODE == 0) ? slot_token[slot] : slot;
        rowA[i] = (u32)src * 1024;
    }
    u32 rowB[2];
    if constexpr (MODE == 0) {
        int r = cb * 64 + wv * 16 + lr;
        rowB[0] = (u32)e * 1048576 + (u32)r * 1024;
        rowB[1] = 0;
    } else {
#pragma unroll
        for (int i = 0; i < 2; i++) {
            int r = cb * 128 + wv * 32 + i * 16 + lr;
            rowB[i] = (u32)e * 1048576 + (u32)r * 1024;
        }
    }

    f32x4 accH[4][NB], accG[(MODE == 0) ? 4 : 1][(MODE == 0) ? NB : 1];
    f32x4 zero = {0.f, 0.f, 0.f, 0.f};
#pragma unroll
    for (int m2 = 0; m2 < 4; m2++)
#pragma unroll
        for (int n = 0; n < NB; n++) accH[m2][n] = zero;
    if constexpr (MODE == 0) {
#pragma unroll
        for (int m2 = 0; m2 < 4; m2++)
#pragma unroll
            for (int n = 0; n < NB; n++) accG[m2][n] = zero;
    }

    auto stage = [&](int buf, int kt) {
        int k0 = kt * 32 + cS;
        gload16(Amat + rowA[0] + k0, sA + buf * 4096 + (wv * 32) * 32);
        gload16(Amat + rowA[1] + k0, sA + buf * 4096 + (wv * 32 + 16) * 32);
        if constexpr (MODE == 0) {
            gload16(B1g + rowB[0] + k0, sB1 + buf * 2048 + (wv * 16) * 32);
            gload16(B2g + rowB[0] + k0, sB2 + buf * 2048 + (wv * 16) * 32);
        } else {
            gload16(B1g + rowB[0] + k0, sB1 + buf * 4096 + (wv * 32) * 32);
            gload16(B1g + rowB[1] + k0, sB1 + buf * 4096 + (wv * 32 + 16) * 32);
        }
    };

    auto compute = [&](int buf) {
        bf16x8 av[4];
#pragma unroll
        for (int m2 = 0; m2 < 4; m2++) {
            int r = wrow * 64 + m2 * 16 + l15;
            av[m2] = *(const bf16x8*)(sA + buf * 4096 + r * 32 + csr);
        }
        bf16x8 b1v[NB];
#pragma unroll
        for (int n = 0; n < NB; n++) {
            int r = wcol * (BN / 2) + n * 16 + l15;
            b1v[n] = *(const bf16x8*)(sB1 + buf * (BN * 32) + r * 32 + csr);
        }
        if constexpr (MODE == 0) {
            bf16x8 b2v[NB];
#pragma unroll
            for (int n = 0; n < NB; n++) {
                int r = wcol * (BN / 2) + n * 16 + l15;
                b2v[n] = *(const bf16x8*)(sB2 + buf * (BN * 32) + r * 32 + csr);
            }
#pragma unroll
            for (int m2 = 0; m2 < 4; m2++)
#pragma unroll
                for (int n = 0; n < NB; n++) {
                    accH[m2][n] = __builtin_amdgcn_mfma_f32_16x16x32_bf16(av[m2], b1v[n], accH[m2][n], 0, 0, 0);
                    accG[m2][n] = __builtin_amdgcn_mfma_f32_16x16x32_bf16(av[m2], b2v[n], accG[m2][n], 0, 0, 0);
                }
        } else {
#pragma unroll
            for (int m2 = 0; m2 < 4; m2++)
#pragma unroll
                for (int n = 0; n < NB; n++)
                    accH[m2][n] = __builtin_amdgcn_mfma_f32_16x16x32_bf16(av[m2], b1v[n], accH[m2][n], 0, 0, 0);
        }
    };

    stage(0, 0);
    for (int kt = 0; kt < NK; ++kt) {
        __syncthreads();
        if (kt + 1 < NK) stage((kt + 1) & 1, kt + 1);
        compute(kt & 1);
    }

    // Epilogue. C/D layout: col = lane&15, row = (lane>>4)*4 + j  [learn_hip m89]
    int colblock = cb * BN + wcol * (BN / 2);
#pragma unroll
    for (int m2 = 0; m2 < 4; m2++) {
        int slotbase = rowbase + wrow * 64 + m2 * 16 + hi * 4;
#pragma unroll
        for (int n = 0; n < NB; n++) {
            int col = colblock + n * 16 + l15;
#pragma unroll
            for (int j = 0; j < 4; j++) {
                int slot = slotbase + j;
                if (slot < segend) {
                    if constexpr (MODE == 0) {
                        float h = accH[m2][n][j], g = accG[m2][n][j];
                        float a = (h / (1.f + __expf(-h))) * g;  // silu(h)*g
                        OutB[(size_t)slot * 1024 + col] = f2bf(a);
                    } else {
                        int tok = slot_token[slot];
                        float wgt = slot_wt[slot];
                        unsafeAtomicAdd(&OutY[(size_t)tok * 1024 + col], accH[m2][n][j] * wgt);
                    }
                }
            }
        }
    }
}

// ---------------- launch ----------------------------------------------------------------
extern "C" void kernel_launch(void* const* d_in, const int* in_sizes, int n_in,
                              void* d_out, int out_size, void* d_ws, size_t ws_size,
                              hipStream_t stream) {
    const float* x  = (const float*)d_in[0];
    const float* gw = (const float*)d_in[1];
    const float* w1 = (const float*)d_in[2];
    const float* w3 = (const float*)d_in[3];
    const float* w2 = (const float*)d_in[4];
    float* y = (float*)d_out;
    char* ws = (char*)d_ws;

    int*   ctl        = (int*)ws;                    // 4 KB control block
    int*   t2i        = (int*)(ws + 4096);           // 32 KB
    float* t2w        = (float*)(ws + 4096 + 32768);
    int*   slot_token = (int*)(ws + 4096 + 65536);
    float* slot_wt    = (float*)(ws + 4096 + 98304);
    u16*   xb   = (u16*)(ws + 262144);               // 4M elems
    u16*   w1b  = xb  + (size_t)4194304;             // 8M elems each
    u16*   w3b  = w1b + (size_t)8388608;
    u16*   w2b  = w3b + (size_t)8388608;
    u16*   Abuf = w2b + (size_t)8388608;             // 8192 x 1024 bf16

    hipMemsetAsync(ctl, 0, 4096, stream);
    hipMemsetAsync(y, 0, (size_t)out_size * sizeof(float), stream);

    cvt_w_kernel<<<2048, 256, 0, stream>>>(w1, w3, w2, w1b);
    gate_kernel<<<1024, 256, 0, stream>>>(x, gw, t2i, t2w, xb);
    sort_kernel<<<1, 1024, 0, stream>>>(t2i, t2w, ctl, slot_token, slot_wt);

    moe_gemm_kernel<0><<<dim3(MAX_TILES, 16), 256, 0, stream>>>(
        xb, w1b, w3b, Abuf, nullptr, ctl, slot_token, slot_wt);
    moe_gemm_kernel<1><<<dim3(MAX_TILES, 8), 256, 0, stream>>>(
        Abuf, w2b, nullptr, nullptr, y, ctl, slot_token, slot_wt);
}

// Round 5
// 163.972 us; speedup vs baseline: 1.9215x; 1.1167x over previous
//
#include <hip/hip_runtime.h>
#include <hip/hip_bf16.h>

typedef unsigned short u16;
typedef unsigned int u32;
typedef __attribute__((ext_vector_type(8))) short bf16x8;
typedef __attribute__((ext_vector_type(4))) float f32x4;

#define NEXP 8
#define NTOK 4096
#define DDIM 1024
#define MAX_TILES 80

__device__ __forceinline__ u16 f2bf(float f) {
    u32 u = __float_as_uint(f);
    u += 0x7fff + ((u >> 16) & 1);  // RNE
    return (u16)(u >> 16);
}

__device__ __forceinline__ void gload16(const void* g, void* l) {
    __builtin_amdgcn_global_load_lds((const __attribute__((address_space(1))) u32*)g,
                                     (__attribute__((address_space(3))) u32*)l, 16, 0, 0);
}

// ---------------- fp32 -> bf16 convert for w1,w3,w2 (contig output) ---------------------
__global__ __launch_bounds__(256) void cvt_w_kernel(const float* __restrict__ w1,
                                                    const float* __restrict__ w3,
                                                    const float* __restrict__ w2,
                                                    u16* __restrict__ out) {
    const int N8 = 3145728;  // 24M / 8
    int stride = gridDim.x * blockDim.x;
    for (int i = blockIdx.x * blockDim.x + threadIdx.x; i < N8; i += stride) {
        const float* src;
        if (i < 1048576)       src = w1 + (size_t)i * 8;
        else if (i < 2097152)  src = w3 + ((size_t)i - 1048576) * 8;
        else                   src = w2 + ((size_t)i - 2097152) * 8;
        float4 a = ((const float4*)src)[0], b = ((const float4*)src)[1];
        uint4 o;
        o.x = (u32)f2bf(a.x) | ((u32)f2bf(a.y) << 16);
        o.y = (u32)f2bf(a.z) | ((u32)f2bf(a.w) << 16);
        o.z = (u32)f2bf(b.x) | ((u32)f2bf(b.y) << 16);
        o.w = (u32)f2bf(b.z) | ((u32)f2bf(b.w) << 16);
        *(uint4*)(out + (size_t)i * 8) = o;
    }
}

// ---------------- gating: wave-per-token; NO atomics; also emits xb (bf16 x) ------------
__global__ __launch_bounds__(256) void gate_kernel(const float* __restrict__ x,
                                                   const float* __restrict__ gw,
                                                   int* __restrict__ t2i, float* __restrict__ t2w,
                                                   u16* __restrict__ xb) {
    int tid = threadIdx.x;
    int wv = tid >> 6, lane = tid & 63;
    int t = blockIdx.x * 4 + wv;
    const float4* xr = (const float4*)(x + (size_t)t * DDIM);
    float4 xv[4];
#pragma unroll
    for (int q = 0; q < 4; q++) xv[q] = xr[lane * 4 + q];

    uint4 o0, o1;
    o0.x = (u32)f2bf(xv[0].x) | ((u32)f2bf(xv[0].y) << 16);
    o0.y = (u32)f2bf(xv[0].z) | ((u32)f2bf(xv[0].w) << 16);
    o0.z = (u32)f2bf(xv[1].x) | ((u32)f2bf(xv[1].y) << 16);
    o0.w = (u32)f2bf(xv[1].z) | ((u32)f2bf(xv[1].w) << 16);
    o1.x = (u32)f2bf(xv[2].x) | ((u32)f2bf(xv[2].y) << 16);
    o1.y = (u32)f2bf(xv[2].z) | ((u32)f2bf(xv[2].w) << 16);
    o1.z = (u32)f2bf(xv[3].x) | ((u32)f2bf(xv[3].y) << 16);
    o1.w = (u32)f2bf(xv[3].z) | ((u32)f2bf(xv[3].w) << 16);
    uint4* xbo = (uint4*)(xb + (size_t)t * DDIM + lane * 16);
    xbo[0] = o0;
    xbo[1] = o1;

    float acc[NEXP];
#pragma unroll
    for (int e = 0; e < NEXP; e++) acc[e] = 0.f;
#pragma unroll
    for (int e = 0; e < NEXP; e++) {
#pragma unroll
        for (int q = 0; q < 4; q++) {
            float4 g = ((const float4*)gw)[e * 256 + lane * 4 + q];
            acc[e] += xv[q].x * g.x + xv[q].y * g.y + xv[q].z * g.z + xv[q].w * g.w;
        }
    }
#pragma unroll
    for (int e = 0; e < NEXP; e++) {
        float v = acc[e];
#pragma unroll
        for (int off = 32; off; off >>= 1) v += __shfl_xor(v, off, 64);
        acc[e] = v;
    }
    if (lane == 0) {
        float m = acc[0];
#pragma unroll
        for (int e = 1; e < NEXP; e++) m = fmaxf(m, acc[e]);
        float p[NEXP]; float s = 0.f;
#pragma unroll
        for (int e = 0; e < NEXP; e++) { p[e] = __expf(acc[e] - m); s += p[e]; }
        float inv = 1.f / s;
        float best = -1.f, sec = -1.f; int bi = 0, si = 0;
#pragma unroll
        for (int e = 0; e < NEXP; e++) {
            float pe = p[e] * inv;
            if (pe > best) { sec = best; si = bi; best = pe; bi = e; }
            else if (pe > sec) { sec = pe; si = e; }
        }
        t2i[2 * t] = bi;  t2i[2 * t + 1] = si;
        t2w[2 * t] = best; t2w[2 * t + 1] = sec;
    }
}

// ---------------- sort: histogram + block scan + stable counting sort (1 block) --------
// ctl layout (ints): [16..25) slot offsets, [24] total, [25] ntiles,
//   [32..112) tile_expert, [112..192) tile_rowbase, [192..272) tile_segend,
//   [280..289) tilestart prefix (per expert)
__global__ __launch_bounds__(1024) void sort_kernel(const int* __restrict__ t2i,
                                                    const float* __restrict__ t2w,
                                                    int* __restrict__ ctl,
                                                    int* __restrict__ slot_token,
                                                    float* __restrict__ slot_wt) {
    __shared__ int sb[NEXP][1024];  // 32 KB
    __shared__ int wsum[16];
    __shared__ int sex[16];
    __shared__ int stot[NEXP];
    __shared__ int soffs[NEXP + 1];
    int tid = threadIdx.x;
    int lane = tid & 63, wv = tid >> 6;

    int4 a = *(const int4*)(t2i + tid * 8);
    int4 b = *(const int4*)(t2i + tid * 8 + 4);
    int ev0 = a.x, ev1 = a.y, ev2 = a.z, ev3 = a.w;
    int ev4 = b.x, ev5 = b.y, ev6 = b.z, ev7 = b.w;
    u32 cnt = (1u << (ev0 * 4)) + (1u << (ev1 * 4)) + (1u << (ev2 * 4)) + (1u << (ev3 * 4)) +
              (1u << (ev4 * 4)) + (1u << (ev5 * 4)) + (1u << (ev6 * 4)) + (1u << (ev7 * 4));

    for (int e = 0; e < NEXP; e++) {
        int v = (cnt >> (e * 4)) & 15;
        int inc = v;
#pragma unroll
        for (int off = 1; off < 64; off <<= 1) {
            int n = __shfl_up(inc, off, 64);
            if (lane >= off) inc += n;
        }
        if (lane == 63) wsum[wv] = inc;
        __syncthreads();
        if (wv == 0) {
            int w = (lane < 16) ? wsum[lane] : 0;
            int winc = w;
#pragma unroll
            for (int off = 1; off < 16; off <<= 1) {
                int n = __shfl_up(winc, off, 64);
                if (lane >= off) winc += n;
            }
            if (lane < 16) sex[lane] = winc - w;
            if (lane == 15) stot[e] = winc;
        }
        __syncthreads();
        sb[e][tid] = sex[wv] + inc - v;
        __syncthreads();
    }
    if (tid == 0) {
        int o = 0, tt = 0;
        for (int e = 0; e < NEXP; e++) {
            soffs[e] = o;
            ctl[16 + e] = o;
            ctl[280 + e] = tt;  // tilestart prefix
            int n = stot[e];
            for (int r = 0; r < n; r += 128) {
                ctl[32 + tt] = e; ctl[112 + tt] = o + r; ctl[192 + tt] = o + n; tt++;
            }
            o += n;
        }
        soffs[NEXP] = o; ctl[24] = o; ctl[25] = tt; ctl[288] = tt;
    }
    __syncthreads();
#pragma unroll
    for (int j = 0; j < 8; j++) {
        int e;
        switch (j) {
            case 0: e = ev0; break; case 1: e = ev1; break; case 2: e = ev2; break;
            case 3: e = ev3; break; case 4: e = ev4; break; case 5: e = ev5; break;
            case 6: e = ev6; break; default: e = ev7; break;
        }
        int base = sb[e][tid];
        sb[e][tid] = base + 1;
        int slot = soffs[e] + base;
        int p = tid * 8 + j;
        slot_token[slot] = p >> 1;
        slot_wt[slot] = t2w[p];
    }
}

// ---------------- expert GEMMs (BK=32, 32KB LDS, 4 blocks/CU) ---------------------------
// 1D grid + bijective XCD swizzle (m204) + (expert, cb, tile) ordering for L2 locality:
// per XCD chunk ~ one expert; per-cb working set ~2.3 MB << 4 MB L2.
template <int MODE>
__global__ __launch_bounds__(256, 4) void moe_gemm_kernel(
    const u16* __restrict__ Amat, const u16* __restrict__ B1g, const u16* __restrict__ B2g,
    u16* __restrict__ OutB, float* __restrict__ OutY,
    const int* __restrict__ ctl, const int* __restrict__ slot_token,
    const float* __restrict__ slot_wt) {
    constexpr int BN = (MODE == 0) ? 64 : 128;
    constexpr int NB = BN / 32;
    constexpr int NCB = DDIM / BN;  // 16 or 8
    constexpr int NK = 32;

    int ntiles = ctl[25];
    int N = ntiles * NCB;
    int bid = blockIdx.x;
    if (bid >= N) return;
    // bijective XCD swizzle: hardware round-robins bid across 8 XCDs; give each XCD a
    // contiguous logical chunk.
    int q = N >> 3, r = N & 7;
    int xcd = bid & 7, seq = bid >> 3;
    int n = (xcd < r ? xcd * (q + 1) : r * (q + 1) + (xcd - r) * q) + seq;
    // decompose n -> (expert e, cb, tile tt), cb-major within expert
    int e = 0, tstart = 0, tiles_e = 0, m = n;
    for (; e < NEXP; e++) {
        tstart = ctl[280 + e];
        tiles_e = ctl[281 + e] - tstart;
        int sz = tiles_e * NCB;
        if (m < sz) break;
        m -= sz;
    }
    if (e == NEXP) return;  // safety
    int cb = m / tiles_e;
    int tt = tstart + (m - cb * tiles_e);
    int rowbase = ctl[112 + tt];
    int segend = ctl[192 + tt];

    __shared__ __align__(16) u16 smem[2 * 128 * 32 + 2 * BN * 32 + ((MODE == 0) ? 2 * 64 * 32 : 0)];
    u16* sA = smem;                  // [2][128][32]
    u16* sB1 = smem + 2 * 128 * 32;  // [2][BN][32]
    u16* sB2 = sB1 + 2 * BN * 32;    // [2][64][32] (MODE 0 only)

    int tid = threadIdx.x;
    int lane = tid & 63;
    int wv = tid >> 6;
    int wrow = wv >> 1, wcol = wv & 1;
    int lr = lane >> 2;
    int cS = (((lane & 3) ^ ((lane >> 3) & 3)) << 3);
    int l15 = lane & 15, hi = lane >> 4;
    int csr = ((hi ^ ((l15 >> 1) & 3)) << 3);

    u32 rowA[2];
#pragma unroll
    for (int i = 0; i < 2; i++) {
        int slot = rowbase + wv * 32 + i * 16 + lr;
        if (slot >= segend) slot = rowbase;
        int src = (MODE == 0) ? slot_token[slot] : slot;
        rowA[i] = (u32)src * 1024;
    }
    u32 rowB[2];
    if constexpr (MODE == 0) {
        int rr = cb * 64 + wv * 16 + lr;
        rowB[0] = (u32)e * 1048576 + (u32)rr * 1024;
        rowB[1] = 0;
    } else {
#pragma unroll
        for (int i = 0; i < 2; i++) {
            int rr = cb * 128 + wv * 32 + i * 16 + lr;
            rowB[i] = (u32)e * 1048576 + (u32)rr * 1024;
        }
    }

    f32x4 accH[4][NB], accG[(MODE == 0) ? 4 : 1][(MODE == 0) ? NB : 1];
    f32x4 zero = {0.f, 0.f, 0.f, 0.f};
#pragma unroll
    for (int m2 = 0; m2 < 4; m2++)
#pragma unroll
        for (int nn = 0; nn < NB; nn++) accH[m2][nn] = zero;
    if constexpr (MODE == 0) {
#pragma unroll
        for (int m2 = 0; m2 < 4; m2++)
#pragma unroll
            for (int nn = 0; nn < NB; nn++) accG[m2][nn] = zero;
    }

    auto stage = [&](int buf, int kt) {
        int k0 = kt * 32 + cS;
        gload16(Amat + rowA[0] + k0, sA + buf * 4096 + (wv * 32) * 32);
        gload16(Amat + rowA[1] + k0, sA + buf * 4096 + (wv * 32 + 16) * 32);
        if constexpr (MODE == 0) {
            gload16(B1g + rowB[0] + k0, sB1 + buf * 2048 + (wv * 16) * 32);
            gload16(B2g + rowB[0] + k0, sB2 + buf * 2048 + (wv * 16) * 32);
        } else {
            gload16(B1g + rowB[0] + k0, sB1 + buf * 4096 + (wv * 32) * 32);
            gload16(B1g + rowB[1] + k0, sB1 + buf * 4096 + (wv * 32 + 16) * 32);
        }
    };

    auto compute = [&](int buf) {
        bf16x8 av[4];
#pragma unroll
        for (int m2 = 0; m2 < 4; m2++) {
            int rr = wrow * 64 + m2 * 16 + l15;
            av[m2] = *(const bf16x8*)(sA + buf * 4096 + rr * 32 + csr);
        }
        bf16x8 b1v[NB];
#pragma unroll
        for (int nn = 0; nn < NB; nn++) {
            int rr = wcol * (BN / 2) + nn * 16 + l15;
            b1v[nn] = *(const bf16x8*)(sB1 + buf * (BN * 32) + rr * 32 + csr);
        }
        if constexpr (MODE == 0) {
            bf16x8 b2v[NB];
#pragma unroll
            for (int nn = 0; nn < NB; nn++) {
                int rr = wcol * (BN / 2) + nn * 16 + l15;
                b2v[nn] = *(const bf16x8*)(sB2 + buf * (BN * 32) + rr * 32 + csr);
            }
#pragma unroll
            for (int m2 = 0; m2 < 4; m2++)
#pragma unroll
                for (int nn = 0; nn < NB; nn++) {
                    accH[m2][nn] = __builtin_amdgcn_mfma_f32_16x16x32_bf16(av[m2], b1v[nn], accH[m2][nn], 0, 0, 0);
                    accG[m2][nn] = __builtin_amdgcn_mfma_f32_16x16x32_bf16(av[m2], b2v[nn], accG[m2][nn], 0, 0, 0);
                }
        } else {
#pragma unroll
            for (int m2 = 0; m2 < 4; m2++)
#pragma unroll
                for (int nn = 0; nn < NB; nn++)
                    accH[m2][nn] = __builtin_amdgcn_mfma_f32_16x16x32_bf16(av[m2], b1v[nn], accH[m2][nn], 0, 0, 0);
        }
    };

    stage(0, 0);
    for (int kt = 0; kt < NK; ++kt) {
        __syncthreads();
        if (kt + 1 < NK) stage((kt + 1) & 1, kt + 1);
        compute(kt & 1);
    }

    // Epilogue. C/D layout: col = lane&15, row = (lane>>4)*4 + j  [learn_hip m89]
    int colblock = cb * BN + wcol * (BN / 2);
#pragma unroll
    for (int m2 = 0; m2 < 4; m2++) {
        int slotbase = rowbase + wrow * 64 + m2 * 16 + hi * 4;
#pragma unroll
        for (int nn = 0; nn < NB; nn++) {
            int col = colblock + nn * 16 + l15;
#pragma unroll
            for (int j = 0; j < 4; j++) {
                int slot = slotbase + j;
                if (slot < segend) {
                    if constexpr (MODE == 0) {
                        float h = accH[m2][nn][j], g = accG[m2][nn][j];
                        float aa = (h / (1.f + __expf(-h))) * g;  // silu(h)*g
                        OutB[(size_t)slot * 1024 + col] = f2bf(aa);
                    } else {
                        int tok = slot_token[slot];
                        float wgt = slot_wt[slot];
                        unsafeAtomicAdd(&OutY[(size_t)tok * 1024 + col], accH[m2][nn][j] * wgt);
                    }
                }
            }
        }
    }
}

// ---------------- launch ----------------------------------------------------------------
extern "C" void kernel_launch(void* const* d_in, const int* in_sizes, int n_in,
                              void* d_out, int out_size, void* d_ws, size_t ws_size,
                              hipStream_t stream) {
    const float* x  = (const float*)d_in[0];
    const float* gw = (const float*)d_in[1];
    const float* w1 = (const float*)d_in[2];
    const float* w3 = (const float*)d_in[3];
    const float* w2 = (const float*)d_in[4];
    float* y = (float*)d_out;
    char* ws = (char*)d_ws;

    int*   ctl        = (int*)ws;                    // 4 KB control block
    int*   t2i        = (int*)(ws + 4096);           // 32 KB
    float* t2w        = (float*)(ws + 4096 + 32768);
    int*   slot_token = (int*)(ws + 4096 + 65536);
    float* slot_wt    = (float*)(ws + 4096 + 98304);
    u16*   xb   = (u16*)(ws + 262144);               // 4M elems
    u16*   w1b  = xb  + (size_t)4194304;             // 8M elems each
    u16*   w3b  = w1b + (size_t)8388608;
    u16*   w2b  = w3b + (size_t)8388608;
    u16*   Abuf = w2b + (size_t)8388608;             // 8192 x 1024 bf16

    hipMemsetAsync(ctl, 0, 4096, stream);
    hipMemsetAsync(y, 0, (size_t)out_size * sizeof(float), stream);

    cvt_w_kernel<<<2048, 256, 0, stream>>>(w1, w3, w2, w1b);
    gate_kernel<<<1024, 256, 0, stream>>>(x, gw, t2i, t2w, xb);
    sort_kernel<<<1, 1024, 0, stream>>>(t2i, t2w, ctl, slot_token, slot_wt);

    moe_gemm_kernel<0><<<MAX_TILES * 16, 256, 0, stream>>>(
        xb, w1b, w3b, Abuf, nullptr, ctl, slot_token, slot_wt);
    moe_gemm_kernel<1><<<MAX_TILES * 8, 256, 0, stream>>>(
        Abuf, w2b, nullptr, nullptr, y, ctl, slot_token, slot_wt);
}